// Round 2
// baseline (126.481 us; speedup 1.0000x reference)
//
#include <hip/hip_runtime.h>

// CatmullRomActivation — MI355X (gfx950), round 7 (resubmit; prior round was an
// infra failure, not a kernel verdict): two-pass, kill the 2nd HBM read of x.
//
// Reference quirk: out.flat[q] needs u from x.flat[q] (linear) and seg from
// x[q%M][q/M] (transposed), cp row q/M. The transpose relation is bipartite
// across blocks (seg-tile of (bi,bj) is the u-region of (32k+bj, bi/4)), so a
// single-pass kernel necessarily reads x twice: 128 MiB R + 64 MiB W = 192 MiB
// -> ~39us at ~5.2 TB/s. L3 does NOT absorb the re-read (reuse distance spans
// up to ~250 MiB of intervening traffic at 256 MiB capacity).
//
// R7: pass 1 reads x once (linear tiles) and writes a 1-byte seg index per
// element in TRANSPOSED layout into d_ws (16 MiB). Pass 2 is a pure linear
// stream: x.flat[q] + segT[q] + 7-entry coef LDS table -> out.flat[q].
// Reuse distance for pass-2's x re-read is <=~100 MiB -> Infinity Cache hit.
// HBM ideal: 64(x) + 16(segT wb) + 64(out) ~= 144 MiB vs 192 MiB.

constexpr int M_DIM  = 8192;   // samples
constexpr int N_DIM  = 2048;   // neurons
constexpr int KPTS   = 10;     // control points per neuron
constexpr int NSEG   = 7;      // segments per neuron (p0 in [1,7])
constexpr size_t SEGT_BYTES = (size_t)M_DIM * N_DIM;   // 16 MiB

typedef float floatx4 __attribute__((ext_vector_type(4)));

__device__ __forceinline__ int seg_of(float v) {
    float p0f = floorf((v + 2.0f) * 1.5f + 1.0f);   // matches ref arithmetic
    int   p0  = (int)p0f;
    p0 = (v <= -2.0f) ? 1 : p0;
    p0 = (v >=  2.0f) ? 7 : p0;
    return p0 - 1;                                   // seg in [0,6]
}

// ---------------- Pass 1: seg bytes, transposed ----------------
// segT[j*M + i] = seg(x[i][j]); 64x64 tile transpose via LDS (dword-packed,
// 4 rows per dword). LDS: 8 insts/thread, 2-way bank conflicts (free).
__global__ __launch_bounds__(256)
void seg_transpose_kernel(const float* __restrict__ x,
                          unsigned char* __restrict__ segT)
{
    __shared__ unsigned int T[64 * 17];   // T[c*17+rg]: rows 4rg..4rg+3 of col c
    const int t  = threadIdx.x;
    const int i0 = blockIdx.x * 64;       // sample (row) tile base
    const int j0 = blockIdx.y * 64;       // neuron (col) tile base
    const int rg = t >> 4;                // 0..15: row group (4 rows)
    const int c0 = (t & 15) << 2;         // 0..60: col base (4 cols)

    unsigned int w0 = 0, w1 = 0, w2 = 0, w3 = 0;
    #pragma unroll
    for (int i = 0; i < 4; ++i) {         // coalesced: 16 lanes x 16B per row
        float4 v = *reinterpret_cast<const float4*>(
            x + (size_t)(i0 + 4 * rg + i) * N_DIM + (j0 + c0));
        w0 |= (unsigned)seg_of(v.x) << (8 * i);
        w1 |= (unsigned)seg_of(v.y) << (8 * i);
        w2 |= (unsigned)seg_of(v.z) << (8 * i);
        w3 |= (unsigned)seg_of(v.w) << (8 * i);
    }
    T[(c0 + 0) * 17 + rg] = w0;
    T[(c0 + 1) * 17 + rg] = w1;
    T[(c0 + 2) * 17 + rg] = w2;
    T[(c0 + 3) * 17 + rg] = w3;
    __syncthreads();

    #pragma unroll
    for (int j = 0; j < 4; ++j) {
        int c = 4 * rg + j;
        unsigned int val = T[c * 17 + (t & 15)];
        // 16 lanes x 4B contiguous per (rg,j): coalesced dword stores
        *reinterpret_cast<unsigned int*>(
            segT + (size_t)(j0 + c) * M_DIM + (i0 + 4 * (t & 15))) = val;
    }
}

// ---------------- Pass 2: pure linear stream ----------------
// Block = 4096 consecutive flat q -> single neuron jq = bid/2.
// 7-entry float4 coef table in LDS: entries hit disjoint bank groups, reads
// are broadcast -> conflict-free.
__global__ __launch_bounds__(256)
void catmull_eval_kernel(const float* __restrict__ x,
                         const float* __restrict__ cp,
                         const unsigned char* __restrict__ segT,
                         float* __restrict__ out)
{
    __shared__ floatx4 coefs[NSEG];
    const int t = threadIdx.x;
    const size_t q0 = (size_t)blockIdx.x * 4096;
    const int jq = blockIdx.x >> 1;                  // q0 / M_DIM

    if (t < NSEG) {
        const float* p = cp + (size_t)jq * KPTS + t;
        float Pm1 = p[0], P0 = p[1], P1 = p[2], P2 = p[3];
        floatx4 cf;
        cf.x =  0.5f * Pm1 - 1.5f * P0 + 1.5f * P1 - 0.5f * P2;
        cf.y = -0.5f * Pm1 + 2.0f * P0 - 2.5f * P1 +        P2;
        cf.z =  0.5f * (P0 - P2);
        cf.w =  P1;
        coefs[t] = cf;
    }

    // Issue all global loads before the barrier (independent of LDS).
    float4 xv[4];
    unsigned int sw[4];
    size_t off[4];
    #pragma unroll
    for (int k = 0; k < 4; ++k) {
        off[k] = q0 + 4 * (size_t)(t + 256 * k);     // per-inst fully coalesced
        xv[k] = *reinterpret_cast<const float4*>(x + off[k]);
        sw[k] = *reinterpret_cast<const unsigned int*>(segT + off[k]);
    }
    __syncthreads();

    #pragma unroll
    for (int k = 0; k < 4; ++k) {
        float xe[4] = {xv[k].x, xv[k].y, xv[k].z, xv[k].w};
        float res[4];
        #pragma unroll
        for (int e = 0; e < 4; ++e) {
            int seg = (sw[k] >> (8 * e)) & 0xff;
            floatx4 cf = coefs[seg];                 // LDS broadcast read
            float tt = 2.0f * xe[e];                 // x / 0.5
            float u  = tt - floorf(tt);
            res[e] = ((cf.x * u + cf.y) * u + cf.z) * u + cf.w;
        }
        floatx4 ov = {res[0], res[1], res[2], res[3]};
        __builtin_nontemporal_store(ov, reinterpret_cast<floatx4*>(out + off[k]));
    }
}

// ---------------- Fallback: R6 single-pass (if ws too small) ----------------
constexpr int TILE   = 64;
constexpr int PITCHW = 17;

__global__ __launch_bounds__(256)
void catmull_rom_fused(const float* __restrict__ x,
                       const float* __restrict__ cp,
                       float* __restrict__ out)
{
    __shared__ unsigned int segp[TILE * PITCHW];
    __shared__ floatx4 coefs[TILE * NSEG];

    const int t   = threadIdx.x;
    const int iq0 = blockIdx.x * TILE;
    const int jq0 = blockIdx.y * TILE;
    const int a   = t >> 4;
    const int g   = (t & 15) << 2;

    float4 tv[4];
    #pragma unroll
    for (int k = 0; k < 4; ++k) {
        int f = t + k * 256;
        int r = f >> 4, c4 = (f & 15) << 2;
        tv[k] = *reinterpret_cast<const float4*>(
            x + (size_t)(iq0 + r) * N_DIM + (jq0 + c4));
    }
    float4 xl[4];
    size_t q[4];
    #pragma unroll
    for (int k = 0; k < 4; ++k) {
        int tj = 4 * a + k;
        q[k]  = (size_t)(jq0 + tj) * M_DIM + (size_t)(iq0 + g);
        xl[k] = *reinterpret_cast<const float4*>(x + q[k]);
    }

    #pragma unroll
    for (int rep = 0; rep < 2; ++rep) {
        int i = t + rep * 256;
        if (i < TILE * NSEG) {
            int n = i / NSEG;
            int s = i - n * NSEG;
            const float* p = cp + (size_t)(jq0 + n) * KPTS + s;
            float Pm1 = p[0], P0 = p[1], P1 = p[2], P2 = p[3];
            floatx4 cf;
            cf.x =  0.5f * Pm1 - 1.5f * P0 + 1.5f * P1 - 0.5f * P2;
            cf.y = -0.5f * Pm1 + 2.0f * P0 - 2.5f * P1 +        P2;
            cf.z =  0.5f * (P0 - P2);
            cf.w =  P1;
            coefs[i] = cf;
        }
    }

    #pragma unroll
    for (int k = 0; k < 4; ++k) {
        int f = t + k * 256;
        int r = f >> 4, c4w = (f & 15);
        unsigned int w = (unsigned)seg_of(tv[k].x)
                       | ((unsigned)seg_of(tv[k].y) << 8)
                       | ((unsigned)seg_of(tv[k].z) << 16)
                       | ((unsigned)seg_of(tv[k].w) << 24);
        segp[r * PITCHW + c4w] = w;
    }
    __syncthreads();

    unsigned int sw[4];
    #pragma unroll
    for (int e = 0; e < 4; ++e)
        sw[e] = segp[(g + e) * PITCHW + a];

    #pragma unroll
    for (int k = 0; k < 4; ++k) {
        int tj = 4 * a + k;
        float xle[4] = {xl[k].x, xl[k].y, xl[k].z, xl[k].w};
        float res[4];
        #pragma unroll
        for (int e = 0; e < 4; ++e) {
            int seg = (sw[e] >> (8 * k)) & 0xff;
            floatx4 cf = coefs[tj * NSEG + seg];
            float xv = xle[e];
            float tt = 2.0f * xv;
            float u  = tt - floorf(tt);
            res[e] = ((cf.x * u + cf.y) * u + cf.z) * u + cf.w;
        }
        floatx4 ov = {res[0], res[1], res[2], res[3]};
        __builtin_nontemporal_store(ov, reinterpret_cast<floatx4*>(out + q[k]));
    }
}

extern "C" void kernel_launch(void* const* d_in, const int* in_sizes, int n_in,
                              void* d_out, int out_size, void* d_ws, size_t ws_size,
                              hipStream_t stream) {
    const float* x  = (const float*)d_in[0];   // (M, N) f32
    const float* cp = (const float*)d_in[1];   // (N, K) f32
    float* out = (float*)d_out;                // (M, N) f32

    if (ws_size >= SEGT_BYTES) {
        unsigned char* segT = (unsigned char*)d_ws;
        seg_transpose_kernel<<<dim3(M_DIM / 64, N_DIM / 64), dim3(256), 0, stream>>>(x, segT);
        catmull_eval_kernel<<<dim3((M_DIM * N_DIM) / 4096), dim3(256), 0, stream>>>(x, cp, segT, out);
    } else {
        catmull_rom_fused<<<dim3(M_DIM / TILE, N_DIM / TILE), dim3(256), 0, stream>>>(x, cp, out);
    }
}

// Round 3
// 115.581 us; speedup vs baseline: 1.0943x; 1.0943x over previous
//
#include <hip/hip_runtime.h>

// CatmullRomActivation — MI355X (gfx950), round 8: back to single-pass; widen
// memory segments 256B -> 512B.
//
// Reference quirk: out.flat[q] needs u from x.flat[q] (linear) and seg from
// x[q%M][q/M] (transposed), cp row q/M. Both x reads are unavoidable in a
// single pass (bipartite producer/consumer relation across blocks); two-pass
// via a seg side-buffer (R7) measured 42.2us vs 39.0us single-pass — L3 gives
// no BW advantage on the re-read, so 192 MiB single-pass is the floor design.
//
// R6 (64x64, 256 thr) = 39.0us = 4.92 TB/s effective vs 6.3 achievable; all
// streams were 256-B strided segments (4 segs/wave-inst). Fills hit 6.3 TB/s
// at 8% occupancy -> occupancy irrelevant; DRAM/fabric efficiency of 256-B
// granules is the suspect. R8: 128x128 tile, 1024 threads, identical per-
// thread structure; every wave-inst now moves 2 x 512-B segments.
// LDS 31.2 KiB: segp write 2-way (free), sw read 4-way (negligible, 4x b32).

constexpr int M_DIM  = 8192;   // samples
constexpr int N_DIM  = 2048;   // neurons
constexpr int KPTS   = 10;     // control points per neuron
constexpr int NSEG   = 7;      // segments per neuron (p0 in [1,7])
constexpr int TI     = 128;    // samples per tile
constexpr int TJ     = 128;    // neurons per tile
constexpr int PITCHW = 33;     // u32 words per seg-pack row (32 + 1 pad)

typedef float floatx4 __attribute__((ext_vector_type(4)));

__device__ __forceinline__ int seg_of(float v) {
    float p0f = floorf((v + 2.0f) * 1.5f + 1.0f);   // matches ref arithmetic
    int   p0  = (int)p0f;
    p0 = (v <= -2.0f) ? 1 : p0;
    p0 = (v >=  2.0f) ? 7 : p0;
    return p0 - 1;                                   // seg in [0,6]
}

__global__ __launch_bounds__(1024)
void catmull_rom_kernel(const float* __restrict__ x,
                        const float* __restrict__ cp,
                        float* __restrict__ out)
{
    __shared__ unsigned int segp[TI * PITCHW];       // 16.9 KB packed segs
    __shared__ floatx4 coefs[TJ * NSEG];             // 14.3 KB cubic coeffs

    const int t   = threadIdx.x;                     // 0..1023
    const int iq0 = blockIdx.x * TI;
    const int jq0 = blockIdx.y * TJ;
    const int a   = t >> 5;            // 0..31  neuron-quad
    const int g   = (t & 31) << 2;     // 0..124 sample base

    // ---- seg-source tile loads: x[iq0+r][jq0+4w..+3] (barrier-critical) ----
    // Per wave-inst: 2 rows x 512 B.
    float4 tv[4];
    #pragma unroll
    for (int k = 0; k < 4; ++k) {
        int f = t + k * 1024;
        int r = f >> 5, c4 = (f & 31) << 2;
        tv[k] = *reinterpret_cast<const float4*>(
            x + (size_t)(iq0 + r) * N_DIM + (jq0 + c4));
    }
    // ---- u loads: linear flat q, LDS-independent, consumed after barrier ----
    // Per wave-inst: 2 neurons x 512 B.
    float4 xl[4];
    size_t q[4];
    #pragma unroll
    for (int k = 0; k < 4; ++k) {
        int tj = 4 * a + k;
        q[k]  = (size_t)(jq0 + tj) * M_DIM + (size_t)(iq0 + g);
        xl[k] = *reinterpret_cast<const float4*>(x + q[k]);
    }

    // ---- cubic coeff table: 896 float4s from global cp (L2-hot) ----
    //   A = 0.5*Pm1 - 1.5*P0 + 1.5*P1 - 0.5*P2
    //   B = -0.5*Pm1 + 2*P0 - 2.5*P1 + P2
    //   C = 0.5*(P0 - P2)
    //   D = P1
    if (t < TJ * NSEG) {
        int n = t / NSEG;                  // neuron-in-tile
        int s = t - n * NSEG;              // segment
        const float* p = cp + (size_t)(jq0 + n) * KPTS + s;
        float Pm1 = p[0], P0 = p[1], P1 = p[2], P2 = p[3];
        floatx4 cf;
        cf.x =  0.5f * Pm1 - 1.5f * P0 + 1.5f * P1 - 0.5f * P2;
        cf.y = -0.5f * Pm1 + 2.0f * P0 - 2.5f * P1 +        P2;
        cf.z =  0.5f * (P0 - P2);
        cf.w =  P1;
        coefs[t] = cf;
    }

    // ---- seg-pack staging: 4 x ds_write_b32, 2-way conflicts (free) ----
    #pragma unroll
    for (int k = 0; k < 4; ++k) {
        int f = t + k * 1024;
        int r = f >> 5, w = f & 31;
        unsigned int pk = (unsigned)seg_of(tv[k].x)
                        | ((unsigned)seg_of(tv[k].y) << 8)
                        | ((unsigned)seg_of(tv[k].z) << 16)
                        | ((unsigned)seg_of(tv[k].w) << 24);
        segp[r * PITCHW + w] = pk;
    }
    __syncthreads();

    // ---- 4 packed seg words serve all 16 outputs ----
    unsigned int sw[4];
    #pragma unroll
    for (int e = 0; e < 4; ++e)
        sw[e] = segp[(g + e) * PITCHW + a];

    // ---- compute + store (per wave-inst: 2 x 512-B NT store segments) ----
    #pragma unroll
    for (int k = 0; k < 4; ++k) {
        int tj = 4 * a + k;
        float xle[4] = {xl[k].x, xl[k].y, xl[k].z, xl[k].w};
        float res[4];
        #pragma unroll
        for (int e = 0; e < 4; ++e) {
            int seg = (sw[e] >> (8 * k)) & 0xff;
            floatx4 cf = coefs[tj * NSEG + seg];   // one ds_read_b128
            float xv = xle[e];
            float tt = 2.0f * xv;                  // x / 0.5
            float u  = tt - floorf(tt);
            res[e] = ((cf.x * u + cf.y) * u + cf.z) * u + cf.w;
        }
        floatx4 ov = {res[0], res[1], res[2], res[3]};
        __builtin_nontemporal_store(ov, reinterpret_cast<floatx4*>(out + q[k]));
    }
}

extern "C" void kernel_launch(void* const* d_in, const int* in_sizes, int n_in,
                              void* d_out, int out_size, void* d_ws, size_t ws_size,
                              hipStream_t stream) {
    const float* x  = (const float*)d_in[0];   // (M, N) f32
    const float* cp = (const float*)d_in[1];   // (N, K) f32
    float* out = (float*)d_out;                // (M, N) f32

    dim3 grid(M_DIM / TI, N_DIM / TJ);         // (64, 16)
    dim3 block(1024);
    catmull_rom_kernel<<<grid, block, 0, stream>>>(x, cp, out);
}